// Round 13
// baseline (165.962 us; speedup 1.0000x reference)
//
#include <hip/hip_runtime.h>

#define PCONST 50
#define ECONST 2000
#define MCONST 64
#define NKEY   (PCONST * ECONST)          // 100000 keys per CSR
#define KPB    256                        // keys per bin
#define NBIN   ((NKEY + KPB - 1) / KPB)   // 391 bins per CSR
#define NBIN2  (2 * NBIN)                 // 782
#define SC_THREADS 512
#define SC_CHUNK   4096                   // facts per block = 8/thread
#define FPT    (SC_CHUNK / SC_THREADS)    // 8
#define CAP    6144                       // bin capacity (mean 5115, +14 sigma, fixed seed)

typedef int ivec4 __attribute__((ext_vector_type(4)));   // nontemporal-store-compatible

// ---------------------------------------------------------------------------
// 1) Two-pass block-sorted slab scatter — bisection variant: 4096-fact
//    chunks x 512 threads (44.6 KB LDS -> 3 resident blocks/CU, 489 blocks)
//    vs R12's 8192x1024 (76.6 KB, 1 block/CU). Wave-shuffle scan kept.
// ---------------------------------------------------------------------------
__global__ void __launch_bounds__(SC_THREADS)
scatter_sort(const int* __restrict__ facts,
             int* __restrict__ bincur,
             unsigned* __restrict__ slab, int F) {
    __shared__ unsigned ordered[2 * SC_CHUNK];   // 32 KB
    __shared__ int cnt[NBIN2];
    __shared__ int lbase[NBIN2];
    __shared__ int cur[NBIN2];
    __shared__ int base[NBIN2];
    __shared__ int wsum[8];

    int t = threadIdx.x;
    int blockStart = blockIdx.x * SC_CHUNK;
    int n = min(SC_CHUNK, F - blockStart);
    if (n <= 0) return;

    for (int i = t; i < NBIN2; i += SC_THREADS) cnt[i] = 0;
    __syncthreads();

    int myBase = blockStart + t * FPT;
    int myN = F - myBase;
    myN = (myN < 0) ? 0 : ((myN > FPT) ? FPT : myN);

    // ---- pass A: count ----
    if (myN == FPT) {
        const int4* p = (const int4*)(facts + 3 * myBase);   // 16B-aligned
        #pragma unroll
        for (int k = 0; k < FPT / 4; ++k) {
            int4 a = p[3 * k], b = p[3 * k + 1], c = p[3 * k + 2];
            atomicAdd(&cnt[(a.x * ECONST + a.y) >> 8], 1);
            atomicAdd(&cnt[NBIN + ((a.x * ECONST + a.z) >> 8)], 1);
            atomicAdd(&cnt[(a.w * ECONST + b.x) >> 8], 1);
            atomicAdd(&cnt[NBIN + ((a.w * ECONST + b.y) >> 8)], 1);
            atomicAdd(&cnt[(b.z * ECONST + b.w) >> 8], 1);
            atomicAdd(&cnt[NBIN + ((b.z * ECONST + c.x) >> 8)], 1);
            atomicAdd(&cnt[(c.y * ECONST + c.z) >> 8], 1);
            atomicAdd(&cnt[NBIN + ((c.y * ECONST + c.w) >> 8)], 1);
        }
    } else {
        for (int i = 0; i < myN; ++i) {
            int g = myBase + i;
            int fp = facts[3 * g], fs = facts[3 * g + 1], fo = facts[3 * g + 2];
            atomicAdd(&cnt[(fp * ECONST + fs) >> 8], 1);
            atomicAdd(&cnt[NBIN + ((fp * ECONST + fo) >> 8)], 1);
        }
    }
    __syncthreads();

    // ---- wave-shuffle exclusive scan of cnt[0..782): 2 bins/thread ----
    {
        int lane = t & 63, w = t >> 6;               // 8 waves
        int b2 = t * 2;
        int c0 = (b2     < NBIN2) ? cnt[b2]     : 0;
        int c1 = (b2 + 1 < NBIN2) ? cnt[b2 + 1] : 0;
        int c = c0 + c1;
        int inc = c;
        for (int d = 1; d < 64; d <<= 1) {
            int v = __shfl_up(inc, d);
            if (lane >= d) inc += v;
        }
        if (lane == 63) wsum[w] = inc;
        __syncthreads();
        int wbase = 0;
        for (int i = 0; i < w; ++i) wbase += wsum[i];
        int excl = wbase + inc - c;
        if (b2 < NBIN2)     { lbase[b2]     = excl; cur[b2]     = excl; }
        if (b2 + 1 < NBIN2) { lbase[b2 + 1] = excl + c0; cur[b2 + 1] = excl + c0; }
    }
    __syncthreads();
    for (int i = t; i < NBIN2; i += SC_THREADS) {
        int c = cnt[i];
        base[i] = c ? atomicAdd(&bincur[i], c) : 0;
    }
    __syncthreads();

    // ---- pass B: re-read facts (L2-hot), scatter into bin-ordered LDS ----
    if (myN == FPT) {
        const int4* p = (const int4*)(facts + 3 * myBase);
        #pragma unroll
        for (int k = 0; k < FPT / 4; ++k) {
            int4 a = p[3 * k], b = p[3 * k + 1], c = p[3 * k + 2];
            int kps, kpo, pos;
            kps = a.x * ECONST + a.y; kpo = a.x * ECONST + a.z;
            pos = atomicAdd(&cur[kps >> 8], 1);
            ordered[pos] = ((unsigned)kps << 11) | (unsigned)a.z;
            pos = atomicAdd(&cur[NBIN + (kpo >> 8)], 1);
            ordered[pos] = (1u << 28) | ((unsigned)kpo << 11) | (unsigned)a.y;
            kps = a.w * ECONST + b.x; kpo = a.w * ECONST + b.y;
            pos = atomicAdd(&cur[kps >> 8], 1);
            ordered[pos] = ((unsigned)kps << 11) | (unsigned)b.y;
            pos = atomicAdd(&cur[NBIN + (kpo >> 8)], 1);
            ordered[pos] = (1u << 28) | ((unsigned)kpo << 11) | (unsigned)b.x;
            kps = b.z * ECONST + b.w; kpo = b.z * ECONST + c.x;
            pos = atomicAdd(&cur[kps >> 8], 1);
            ordered[pos] = ((unsigned)kps << 11) | (unsigned)c.x;
            pos = atomicAdd(&cur[NBIN + (kpo >> 8)], 1);
            ordered[pos] = (1u << 28) | ((unsigned)kpo << 11) | (unsigned)b.w;
            kps = c.y * ECONST + c.z; kpo = c.y * ECONST + c.w;
            pos = atomicAdd(&cur[kps >> 8], 1);
            ordered[pos] = ((unsigned)kps << 11) | (unsigned)c.w;
            pos = atomicAdd(&cur[NBIN + (kpo >> 8)], 1);
            ordered[pos] = (1u << 28) | ((unsigned)kpo << 11) | (unsigned)c.z;
        }
    } else {
        for (int i = 0; i < myN; ++i) {
            int g = myBase + i;
            int fp = facts[3 * g], fs = facts[3 * g + 1], fo = facts[3 * g + 2];
            int kps = fp * ECONST + fs;
            int kpo = fp * ECONST + fo;
            int pos = atomicAdd(&cur[kps >> 8], 1);
            ordered[pos] = ((unsigned)kps << 11) | (unsigned)fo;
            pos = atomicAdd(&cur[NBIN + (kpo >> 8)], 1);
            ordered[pos] = (1u << 28) | ((unsigned)kpo << 11) | (unsigned)fs;
        }
    }
    __syncthreads();

    // ---- write-out: flat, lane-coalesced ----
    int n2 = 2 * n;
    for (int j = t; j < n2; j += SC_THREADS) {
        unsigned v = ordered[j];
        int cbin = (int)((v >> 19) & 511u) + ((v >> 28) ? NBIN : 0);
        int pos  = base[cbin] + (j - lbase[cbin]);
        if (pos < CAP) slab[(size_t)cbin * CAP + pos] = v & 0x0FFFFFFFu;
    }
}

// ---------------------------------------------------------------------------
// 2) Per-bin LDS counting sort + per-key insertion sort (R12, unchanged).
// ---------------------------------------------------------------------------
__global__ void binsort_kernel(const int* __restrict__ bincur,
                               const unsigned* __restrict__ slab,
                               int* __restrict__ off_ps,
                               int* __restrict__ off_po,
                               unsigned short* __restrict__ data_ps,
                               unsigned short* __restrict__ data_po, int F) {
    __shared__ unsigned buf[CAP];          // 24 KB
    __shared__ unsigned short outv[CAP];   // 12 KB
    __shared__ int hist[KPB];              // 1 KB
    __shared__ int partial[KPB];           // 1 KB
    __shared__ int red[4];

    int wg = blockIdx.x;
    int* offout;
    unsigned short* data;
    const int* curbase;
    int b;
    if (wg < NBIN) { offout = off_ps; data = data_ps; curbase = bincur;        b = wg; }
    else           { offout = off_po; data = data_po; curbase = bincur + NBIN; b = wg - NBIN; }
    int t = threadIdx.x;

    // compacted base = sum of this CSR's cursors for bins < b
    int s = 0;
    for (int i = t; i < b; i += KPB) s += curbase[i];
    for (int d = 1; d < 64; d <<= 1) s += __shfl_xor(s, d);
    int lane = t & 63, wv = t >> 6;
    if (lane == 0) red[wv] = s;
    __syncthreads();
    int start = red[0] + red[1] + red[2] + red[3];

    int key0 = b * KPB;
    int len  = min(curbase[b], CAP);
    const unsigned* src = slab + (size_t)wg * CAP;

    if (t == 0 && b == 0) offout[NKEY] = F;      // sentinel for query's off[key+1]

    for (int i = t; i < len; i += KPB) buf[i] = src[i];
    hist[t] = 0;
    __syncthreads();
    for (int i = t; i < len; i += KPB)
        atomicAdd(&hist[(int)(buf[i] >> 11) - key0], 1);
    __syncthreads();

    // exclusive scan of hist[0..256)
    partial[t] = hist[t];
    __syncthreads();
    for (int d = 1; d < KPB; d <<= 1) {
        int v = (t >= d) ? partial[t - d] : 0;
        __syncthreads();
        partial[t] += v;
        __syncthreads();
    }
    int excl = (t == 0) ? 0 : partial[t - 1];
    int gk = key0 + t;
    if (gk < NKEY) offout[gk] = start + excl;    // key-level off table
    hist[t] = excl;
    __syncthreads();

    // LDS scatter by key (hist becomes cursor; afterwards hist[k] = end of k)
    for (int i = t; i < len; i += KPB) {
        unsigned v = buf[i];
        int lk  = (int)(v >> 11) - key0;
        int pos = atomicAdd(&hist[lk], 1);
        outv[pos] = (unsigned short)(v & 2047u);
    }
    __syncthreads();

    // per-key ascending insertion sort: thread t owns key key0+t (avg run ~20)
    {
        int s0 = (t == 0) ? 0 : hist[t - 1];
        int e0 = hist[t];
        for (int i = s0 + 1; i < e0; ++i) {
            unsigned short v = outv[i]; int j = i - 1;
            while (j >= s0 && outv[j] > v) { outv[j + 1] = outv[j]; --j; }
            outv[j + 1] = v;
        }
    }
    __syncthreads();

    for (int i = t; i < len; i += KPB) data[start + i] = outv[i];
}

// ---------------------------------------------------------------------------
// 3) Queries, wave-batched, 4 queries per iteration (R12, unchanged).
// ---------------------------------------------------------------------------
__global__ void query_kernel(const int* __restrict__ preds,
                             const int* __restrict__ bound,
                             const int* __restrict__ dir,
                             const int* __restrict__ off_ps,
                             const int* __restrict__ off_po,
                             const unsigned short* __restrict__ vals_ps,
                             const unsigned short* __restrict__ vals_po,
                             int* __restrict__ cand,
                             int* __restrict__ valid, int N, int F) {
    int gwave  = (blockIdx.x * blockDim.x + threadIdx.x) >> 6;
    int lane   = threadIdx.x & 63;
    int nwaves = (gridDim.x * blockDim.x) >> 6;
    int grp = lane >> 4;             // which of the 4 queries in this iteration
    int sl  = (lane & 15) * 4;       // slot base 0..60

    for (int qb = gwave * 64; qb < N; qb += nwaves * 64) {
        int q = qb + lane;
        unsigned pk = 0;
        if (q < N) {
            int key = preds[q] * ECONST + bound[q];
            int dd  = dir[q];
            const int* off = (dd == 0) ? off_ps : off_po;
            int s0 = off[key];
            int c0 = min(off[key + 1] - s0, MCONST);
            if (c0 < 0) c0 = 0;
            pk = ((unsigned)s0 << 9) | ((unsigned)(dd != 0) << 8) | (unsigned)c0;
        }
        int nq = min(64, N - qb);
        for (int j4 = 0; j4 < nq; j4 += 4) {
            int j = j4 + grp;
            unsigned pj = (unsigned)__shfl((int)pk, j);
            if (j < nq) {
                int c  = (int)(pj & 255u);
                int s  = (int)(pj >> 9);
                const unsigned short* vals = (pj & 256u) ? vals_po : vals_ps;
                ivec4 cv, vv;
                int g0 = min(s + sl,     F - 1);   // reference gathers clipped garbage
                int g1 = min(s + sl + 1, F - 1);
                int g2 = min(s + sl + 2, F - 1);
                int g3 = min(s + sl + 3, F - 1);
                cv.x = (int)vals[g0];
                cv.y = (int)vals[g1];
                cv.z = (int)vals[g2];
                cv.w = (int)vals[g3];
                vv.x = (sl     < c) ? 1 : 0;
                vv.y = (sl + 1 < c) ? 1 : 0;
                vv.z = (sl + 2 < c) ? 1 : 0;
                vv.w = (sl + 3 < c) ? 1 : 0;
                size_t o = (size_t)(qb + j) * MCONST + sl;   // 16B-aligned (sl%4==0)
                __builtin_nontemporal_store(cv, (ivec4*)&cand[o]);
                __builtin_nontemporal_store(vv, (ivec4*)&valid[o]);
            }
        }
    }
}

// ---------------------------------------------------------------------------
extern "C" void kernel_launch(void* const* d_in, const int* in_sizes, int n_in,
                              void* d_out, int out_size, void* d_ws, size_t ws_size,
                              hipStream_t stream) {
    const int* facts = (const int*)d_in[0];
    const int* preds = (const int*)d_in[1];
    const int* bound = (const int*)d_in[2];
    const int* dir   = (const int*)d_in[3];
    int F = in_sizes[0] / 3;
    int N = in_sizes[1];

    // Workspace layout (int32 units)
    int* ws       = (int*)d_ws;
    int* off_ps   = ws;                          // NKEY+4
    int* off_po   = off_ps + NKEY + 4;           // NKEY+4
    int* bincur   = off_po + NKEY + 4;           // NBIN2
    int* pad      = bincur + NBIN2;
    size_t ofs = (size_t)(pad - ws);
    ofs = (ofs + 3) & ~(size_t)3;                // 16B-align
    unsigned short* data_ps = (unsigned short*)(ws + ofs);        // F u16
    unsigned short* data_po = data_ps + F;                        // F u16
    unsigned* slab = (unsigned*)(data_po + F);   // [NBIN2][CAP] u32 = 19.2 MB

    hipMemsetAsync(bincur, 0, (size_t)NBIN2 * sizeof(int), stream);

    int nChunks = (F + SC_CHUNK - 1) / SC_CHUNK;
    scatter_sort<<<nChunks, SC_THREADS, 0, stream>>>(facts, bincur, slab, F);
    binsort_kernel<<<NBIN2, KPB, 0, stream>>>(bincur, slab,
                                              off_ps, off_po, data_ps, data_po, F);

    int* cand  = (int*)d_out;
    int* valid = cand + (size_t)N * MCONST;
    int qBlocks = (N / 64 + 3) / 4 + 1;          // ~1954 blocks, 4 waves each
    query_kernel<<<qBlocks, 256, 0, stream>>>(
        preds, bound, dir, off_ps, off_po, data_ps, data_po, cand, valid, N, F);
}

// Round 14
// 152.995 us; speedup vs baseline: 1.0848x; 1.0848x over previous
//
#include <hip/hip_runtime.h>

#define PCONST 50
#define ECONST 2000
#define MCONST 64
#define NKEY   (PCONST * ECONST)          // 100000 keys per CSR
#define KPB    256                        // keys per bin
#define NBIN   ((NKEY + KPB - 1) / KPB)   // 391 bins per CSR
#define NBIN2  (2 * NBIN)                 // 782
#define SC_THREADS 1024
#define SC_CHUNK   8192                   // facts per block = 8/thread -> 84B runs/bin
#define FPT    (SC_CHUNK / SC_THREADS)    // 8
#define CAP    6144                       // bin capacity (mean 5115, +14 sigma, fixed seed)

typedef int ivec4 __attribute__((ext_vector_type(4)));   // nontemporal-store-compatible

// ---------------------------------------------------------------------------
// 1) Two-pass block-sorted slab scatter — R12 geometry (245 blocks x 1024
//    threads, 8192-fact chunks, 21-elem runs) + register carry: packed pairs
//    stay in 16 VGPRs between count and scatter (no pass-B fact re-read).
// ---------------------------------------------------------------------------
__global__ void __launch_bounds__(SC_THREADS)
scatter_sort(const int* __restrict__ facts,
             int* __restrict__ bincur,
             unsigned* __restrict__ slab, int F) {
    __shared__ unsigned ordered[2 * SC_CHUNK];   // 64 KB
    __shared__ int cnt[NBIN2];
    __shared__ int lbase[NBIN2];
    __shared__ int cur[NBIN2];
    __shared__ int base[NBIN2];
    __shared__ int wsum[16];

    int t = threadIdx.x;
    int blockStart = blockIdx.x * SC_CHUNK;
    int n = min(SC_CHUNK, F - blockStart);
    if (n <= 0) return;

    for (int i = t; i < NBIN2; i += SC_THREADS) cnt[i] = 0;
    __syncthreads();

    int myBase = blockStart + t * FPT;
    int myN = F - myBase;
    myN = (myN < 0) ? 0 : ((myN > FPT) ? FPT : myN);

    unsigned vps[FPT], vpo[FPT];                 // register-carried packed pairs

    // ---- pass A: load + pack into regs + count ----
    if (myN == FPT) {
        const int4* p = (const int4*)(facts + 3 * myBase);   // 16B-aligned
        int4 w0 = p[0], w1 = p[1], w2 = p[2], w3 = p[3], w4 = p[4], w5 = p[5];
        int kps, kpo;
        kps = w0.x * ECONST + w0.y; kpo = w0.x * ECONST + w0.z;
        vps[0] = ((unsigned)kps << 11) | (unsigned)w0.z;
        vpo[0] = ((unsigned)kpo << 11) | (unsigned)w0.y;
        atomicAdd(&cnt[kps >> 8], 1); atomicAdd(&cnt[NBIN + (kpo >> 8)], 1);
        kps = w0.w * ECONST + w1.x; kpo = w0.w * ECONST + w1.y;
        vps[1] = ((unsigned)kps << 11) | (unsigned)w1.y;
        vpo[1] = ((unsigned)kpo << 11) | (unsigned)w1.x;
        atomicAdd(&cnt[kps >> 8], 1); atomicAdd(&cnt[NBIN + (kpo >> 8)], 1);
        kps = w1.z * ECONST + w1.w; kpo = w1.z * ECONST + w2.x;
        vps[2] = ((unsigned)kps << 11) | (unsigned)w2.x;
        vpo[2] = ((unsigned)kpo << 11) | (unsigned)w1.w;
        atomicAdd(&cnt[kps >> 8], 1); atomicAdd(&cnt[NBIN + (kpo >> 8)], 1);
        kps = w2.y * ECONST + w2.z; kpo = w2.y * ECONST + w2.w;
        vps[3] = ((unsigned)kps << 11) | (unsigned)w2.w;
        vpo[3] = ((unsigned)kpo << 11) | (unsigned)w2.z;
        atomicAdd(&cnt[kps >> 8], 1); atomicAdd(&cnt[NBIN + (kpo >> 8)], 1);
        kps = w3.x * ECONST + w3.y; kpo = w3.x * ECONST + w3.z;
        vps[4] = ((unsigned)kps << 11) | (unsigned)w3.z;
        vpo[4] = ((unsigned)kpo << 11) | (unsigned)w3.y;
        atomicAdd(&cnt[kps >> 8], 1); atomicAdd(&cnt[NBIN + (kpo >> 8)], 1);
        kps = w3.w * ECONST + w4.x; kpo = w3.w * ECONST + w4.y;
        vps[5] = ((unsigned)kps << 11) | (unsigned)w4.y;
        vpo[5] = ((unsigned)kpo << 11) | (unsigned)w4.x;
        atomicAdd(&cnt[kps >> 8], 1); atomicAdd(&cnt[NBIN + (kpo >> 8)], 1);
        kps = w4.z * ECONST + w4.w; kpo = w4.z * ECONST + w5.x;
        vps[6] = ((unsigned)kps << 11) | (unsigned)w5.x;
        vpo[6] = ((unsigned)kpo << 11) | (unsigned)w4.w;
        atomicAdd(&cnt[kps >> 8], 1); atomicAdd(&cnt[NBIN + (kpo >> 8)], 1);
        kps = w5.y * ECONST + w5.z; kpo = w5.y * ECONST + w5.w;
        vps[7] = ((unsigned)kps << 11) | (unsigned)w5.w;
        vpo[7] = ((unsigned)kpo << 11) | (unsigned)w5.z;
        atomicAdd(&cnt[kps >> 8], 1); atomicAdd(&cnt[NBIN + (kpo >> 8)], 1);
    } else {
        for (int i = 0; i < myN; ++i) {
            int g = myBase + i;
            int fp = facts[3 * g], fs = facts[3 * g + 1], fo = facts[3 * g + 2];
            int kps = fp * ECONST + fs;
            int kpo = fp * ECONST + fo;
            vps[i] = ((unsigned)kps << 11) | (unsigned)fo;
            vpo[i] = ((unsigned)kpo << 11) | (unsigned)fs;
            atomicAdd(&cnt[kps >> 8], 1);
            atomicAdd(&cnt[NBIN + (kpo >> 8)], 1);
        }
    }
    __syncthreads();

    // ---- wave-shuffle exclusive scan of cnt[0..782) -> lbase, cur ----
    {
        int lane = t & 63, w = t >> 6;              // 16 waves, waves 0..12 used
        int c = (t < NBIN2) ? cnt[t] : 0;
        int inc = c;
        for (int d = 1; d < 64; d <<= 1) {
            int v = __shfl_up(inc, d);
            if (lane >= d) inc += v;
        }
        if (lane == 63) wsum[w] = inc;
        __syncthreads();
        if (t < NBIN2) {
            int wbase = 0;
            for (int i = 0; i < w; ++i) wbase += wsum[i];
            int excl = wbase + inc - c;
            lbase[t] = excl;
            cur[t]   = excl;
        }
    }
    __syncthreads();
    for (int i = t; i < NBIN2; i += SC_THREADS) {
        int c = cnt[i];
        base[i] = c ? atomicAdd(&bincur[i], c) : 0;
    }
    __syncthreads();

    // ---- pass B: scatter from registers into bin-ordered LDS ----
    #pragma unroll
    for (int i = 0; i < FPT; ++i) {
        if (i >= myN) break;
        unsigned ps = vps[i];
        int pos = atomicAdd(&cur[ps >> 19], 1);
        ordered[pos] = ps;
        unsigned po = vpo[i];
        pos = atomicAdd(&cur[NBIN + (po >> 19)], 1);
        ordered[pos] = (1u << 28) | po;
    }
    __syncthreads();

    // ---- write-out: flat, lane-coalesced ----
    int n2 = 2 * n;
    for (int j = t; j < n2; j += SC_THREADS) {
        unsigned v = ordered[j];
        int cbin = (int)((v >> 19) & 511u) + ((v >> 28) ? NBIN : 0);
        int pos  = base[cbin] + (j - lbase[cbin]);
        if (pos < CAP) slab[(size_t)cbin * CAP + pos] = v & 0x0FFFFFFFu;
    }
}

// ---------------------------------------------------------------------------
// 2) Per-bin LDS counting sort + per-key insertion sort (R12 + wave-scan).
// ---------------------------------------------------------------------------
__global__ void binsort_kernel(const int* __restrict__ bincur,
                               const unsigned* __restrict__ slab,
                               int* __restrict__ off_ps,
                               int* __restrict__ off_po,
                               unsigned short* __restrict__ data_ps,
                               unsigned short* __restrict__ data_po, int F) {
    __shared__ unsigned buf[CAP];          // 24 KB
    __shared__ unsigned short outv[CAP];   // 12 KB
    __shared__ int hist[KPB];              // 1 KB
    __shared__ int wsum[4];
    __shared__ int red[4];

    int wg = blockIdx.x;
    int* offout;
    unsigned short* data;
    const int* curbase;
    int b;
    if (wg < NBIN) { offout = off_ps; data = data_ps; curbase = bincur;        b = wg; }
    else           { offout = off_po; data = data_po; curbase = bincur + NBIN; b = wg - NBIN; }
    int t = threadIdx.x;
    int lane = t & 63, w = t >> 6;

    // compacted base = sum of this CSR's cursors for bins < b
    int s = 0;
    for (int i = t; i < b; i += KPB) s += curbase[i];
    for (int d = 1; d < 64; d <<= 1) s += __shfl_xor(s, d);
    if (lane == 0) red[w] = s;
    __syncthreads();
    int start = red[0] + red[1] + red[2] + red[3];

    int key0 = b * KPB;
    int len  = min(curbase[b], CAP);
    const unsigned* src = slab + (size_t)wg * CAP;

    if (t == 0 && b == 0) offout[NKEY] = F;      // sentinel for query's off[key+1]

    for (int i = t; i < len; i += KPB) buf[i] = src[i];
    hist[t] = 0;
    __syncthreads();
    for (int i = t; i < len; i += KPB)
        atomicAdd(&hist[(int)(buf[i] >> 11) - key0], 1);
    __syncthreads();

    // wave-shuffle exclusive scan of hist[0..256)
    int c = hist[t];
    int inc = c;
    for (int d = 1; d < 64; d <<= 1) {
        int v = __shfl_up(inc, d);
        if (lane >= d) inc += v;
    }
    if (lane == 63) wsum[w] = inc;
    __syncthreads();
    int wbase = 0;
    for (int i = 0; i < w; ++i) wbase += wsum[i];
    int excl = wbase + inc - c;
    int gk = key0 + t;
    if (gk < NKEY) offout[gk] = start + excl;    // key-level off table
    __syncthreads();                             // hist reads done before overwrite
    hist[t] = excl;
    __syncthreads();

    // LDS scatter by key (hist becomes cursor; afterwards hist[k] = end of k)
    for (int i = t; i < len; i += KPB) {
        unsigned v = buf[i];
        int lk  = (int)(v >> 11) - key0;
        int pos = atomicAdd(&hist[lk], 1);
        outv[pos] = (unsigned short)(v & 2047u);
    }
    __syncthreads();

    // per-key ascending insertion sort: thread t owns key key0+t (avg run ~20)
    {
        int s0 = (t == 0) ? 0 : hist[t - 1];
        int e0 = hist[t];
        for (int i = s0 + 1; i < e0; ++i) {
            unsigned short v = outv[i]; int j = i - 1;
            while (j >= s0 && outv[j] > v) { outv[j + 1] = outv[j]; --j; }
            outv[j + 1] = v;
        }
    }
    __syncthreads();

    for (int i = t; i < len; i += KPB) data[start + i] = outv[i];
}

// ---------------------------------------------------------------------------
// 3) Queries, wave-batched, 4 queries per iteration (R12, unchanged).
// ---------------------------------------------------------------------------
__global__ void query_kernel(const int* __restrict__ preds,
                             const int* __restrict__ bound,
                             const int* __restrict__ dir,
                             const int* __restrict__ off_ps,
                             const int* __restrict__ off_po,
                             const unsigned short* __restrict__ vals_ps,
                             const unsigned short* __restrict__ vals_po,
                             int* __restrict__ cand,
                             int* __restrict__ valid, int N, int F) {
    int gwave  = (blockIdx.x * blockDim.x + threadIdx.x) >> 6;
    int lane   = threadIdx.x & 63;
    int nwaves = (gridDim.x * blockDim.x) >> 6;
    int grp = lane >> 4;             // which of the 4 queries in this iteration
    int sl  = (lane & 15) * 4;       // slot base 0..60

    for (int qb = gwave * 64; qb < N; qb += nwaves * 64) {
        int q = qb + lane;
        unsigned pk = 0;
        if (q < N) {
            int key = preds[q] * ECONST + bound[q];
            int dd  = dir[q];
            const int* off = (dd == 0) ? off_ps : off_po;
            int s0 = off[key];
            int c0 = min(off[key + 1] - s0, MCONST);
            if (c0 < 0) c0 = 0;
            pk = ((unsigned)s0 << 9) | ((unsigned)(dd != 0) << 8) | (unsigned)c0;
        }
        int nq = min(64, N - qb);
        for (int j4 = 0; j4 < nq; j4 += 4) {
            int j = j4 + grp;
            unsigned pj = (unsigned)__shfl((int)pk, j);
            if (j < nq) {
                int c  = (int)(pj & 255u);
                int s  = (int)(pj >> 9);
                const unsigned short* vals = (pj & 256u) ? vals_po : vals_ps;
                ivec4 cv, vv;
                int g0 = min(s + sl,     F - 1);   // reference gathers clipped garbage
                int g1 = min(s + sl + 1, F - 1);
                int g2 = min(s + sl + 2, F - 1);
                int g3 = min(s + sl + 3, F - 1);
                cv.x = (int)vals[g0];
                cv.y = (int)vals[g1];
                cv.z = (int)vals[g2];
                cv.w = (int)vals[g3];
                vv.x = (sl     < c) ? 1 : 0;
                vv.y = (sl + 1 < c) ? 1 : 0;
                vv.z = (sl + 2 < c) ? 1 : 0;
                vv.w = (sl + 3 < c) ? 1 : 0;
                size_t o = (size_t)(qb + j) * MCONST + sl;   // 16B-aligned (sl%4==0)
                __builtin_nontemporal_store(cv, (ivec4*)&cand[o]);
                __builtin_nontemporal_store(vv, (ivec4*)&valid[o]);
            }
        }
    }
}

// ---------------------------------------------------------------------------
extern "C" void kernel_launch(void* const* d_in, const int* in_sizes, int n_in,
                              void* d_out, int out_size, void* d_ws, size_t ws_size,
                              hipStream_t stream) {
    const int* facts = (const int*)d_in[0];
    const int* preds = (const int*)d_in[1];
    const int* bound = (const int*)d_in[2];
    const int* dir   = (const int*)d_in[3];
    int F = in_sizes[0] / 3;
    int N = in_sizes[1];

    // Workspace layout (int32 units)
    int* ws       = (int*)d_ws;
    int* off_ps   = ws;                          // NKEY+4
    int* off_po   = off_ps + NKEY + 4;           // NKEY+4
    int* bincur   = off_po + NKEY + 4;           // NBIN2
    int* pad      = bincur + NBIN2;
    size_t ofs = (size_t)(pad - ws);
    ofs = (ofs + 3) & ~(size_t)3;                // 16B-align
    unsigned short* data_ps = (unsigned short*)(ws + ofs);        // F u16
    unsigned short* data_po = data_ps + F;                        // F u16
    unsigned* slab = (unsigned*)(data_po + F);   // [NBIN2][CAP] u32 = 19.2 MB

    hipMemsetAsync(bincur, 0, (size_t)NBIN2 * sizeof(int), stream);

    int nChunks = (F + SC_CHUNK - 1) / SC_CHUNK;
    scatter_sort<<<nChunks, SC_THREADS, 0, stream>>>(facts, bincur, slab, F);
    binsort_kernel<<<NBIN2, KPB, 0, stream>>>(bincur, slab,
                                              off_ps, off_po, data_ps, data_po, F);

    int* cand  = (int*)d_out;
    int* valid = cand + (size_t)N * MCONST;
    int qBlocks = (N / 64 + 3) / 4 + 1;          // ~1954 blocks, 4 waves each
    query_kernel<<<qBlocks, 256, 0, stream>>>(
        preds, bound, dir, off_ps, off_po, data_ps, data_po, cand, valid, N, F);
}